// Round 11
// baseline (265.226 us; speedup 1.0000x reference)
//
#include <hip/hip_runtime.h>
#include <hip/hip_bf16.h>

typedef unsigned short ushort_t;
typedef unsigned int uint_t;

typedef __attribute__((ext_vector_type(8))) short bf8;
typedef __attribute__((ext_vector_type(4))) float f4;
typedef __attribute__((ext_vector_type(16))) float f16v;

__device__ __forceinline__ float bf2f(ushort_t u) {
    unsigned int x = ((unsigned int)u) << 16;
    return __uint_as_float(x);
}
__device__ __forceinline__ ushort_t f2bf(float f) {
    unsigned int x = __float_as_uint(f);
    unsigned int r = x + 0x7fffu + ((x >> 16) & 1u);
    return (ushort_t)(r >> 16);
}
__device__ __forceinline__ uint_t pack2bf(float a, float b) {
    return (uint_t)f2bf(a) | ((uint_t)f2bf(b) << 16);
}
// fast pack: round-half-up + v_perm_b32 byte gather (3 VALU vs ~9)
__device__ __forceinline__ uint_t pack2bf_fast(float a, float b) {
    uint_t au = __float_as_uint(a) + 0x8000u;
    uint_t bu = __float_as_uint(b) + 0x8000u;
    return __builtin_amdgcn_perm(bu, au, 0x07060302);  // lo16=a_hi, hi16=b_hi
}

__device__ __forceinline__ void gl2lds16(const ushort_t* g, ushort_t* l) {
    __builtin_amdgcn_global_load_lds(
        (const __attribute__((address_space(1))) void*)g,
        (__attribute__((address_space(3))) void*)l, 16, 0, 0);
}

// ---------------------------------------------------------------------------
// prep (merged): [0,4096) x fp32->bf16; [4096,4224) Wg pack; [4224,8320)
// weight transpose-convert (4 matrices, 32x32 tiles)
// ---------------------------------------------------------------------------
__global__ __launch_bounds__(256)
void prep(const float* __restrict__ x, ushort_t* __restrict__ xb,
          const float* __restrict__ Wr, const float* __restrict__ Ws,
          ushort_t* __restrict__ Wg,
          const float* __restrict__ W0, const float* __restrict__ W1,
          const float* __restrict__ W2, const float* __restrict__ W3,
          ushort_t* __restrict__ T0, ushort_t* __restrict__ T1,
          ushort_t* __restrict__ T2, ushort_t* __restrict__ T3)
{
    __shared__ float tile[32][33];
    int bid = blockIdx.x;
    int t = threadIdx.x;
    if (bid < 4096) {
        int i = bid * 256 + t;
        float4 v = ((const float4*)x)[i];
        uint2 o;
        o.x = pack2bf(v.x, v.y);
        o.y = pack2bf(v.z, v.w);
        ((uint2*)xb)[i] = o;
    } else if (bid < 4224) {
        int idx = (bid - 4096) * 256 + t;   // 32 x 1024
        int c = idx >> 10, d = idx & 1023;
        float v = 0.f;
        if (c < 15) v = Wr[(size_t)d * 15 + c];
        else if (c < 17) v = Ws[(size_t)d * 2 + (c - 15)];
        Wg[idx] = f2bf(v);
    } else {
        int idx = bid - 4224;               // 4 x 32 x 32 tiles
        int z = idx >> 10, r10 = idx & 1023;
        int k0 = (r10 & 31) * 32, n0 = (r10 >> 5) * 32;
        const float* W; ushort_t* T;
        switch (z) {
            case 0: W = W0; T = T0; break;
            case 1: W = W1; T = T1; break;
            case 2: W = W2; T = T2; break;
            default: W = W3; T = T3; break;
        }
        int r = t >> 3, c4 = (t & 7) * 4;
        float4 v = *(const float4*)&W[(size_t)(k0 + r) * 1024 + n0 + c4];
        tile[r][c4 + 0] = v.x; tile[r][c4 + 1] = v.y;
        tile[r][c4 + 2] = v.z; tile[r][c4 + 3] = v.w;
        __syncthreads();
        int n = t >> 3, kk = (t & 7) * 4;
        uint2 o;
        o.x = pack2bf(tile[kk][n], tile[kk + 1][n]);
        o.y = pack2bf(tile[kk + 2][n], tile[kk + 3][n]);
        *(uint2*)&T[(size_t)(n0 + n) * 1024 + k0 + kk] = o;
    }
}

// ---------------------------------------------------------------------------
// Fused QKV GEMM: [4096x1024] @ Wt3[3072,1024]^T. Grid (32, 24).
// region = y>>3: 0=Q, 1=K, 2=V. (unchanged)
// ---------------------------------------------------------------------------
__global__ __launch_bounds__(256)
void gemmQKV(const ushort_t* __restrict__ A, const ushort_t* __restrict__ Wt3,
             const float* __restrict__ bq, const float* __restrict__ bk,
             const float* __restrict__ bv,
             ushort_t* __restrict__ Qb, ushort_t* __restrict__ Kw,
             ushort_t* __restrict__ VTw,
             const float* __restrict__ temp, const float* __restrict__ emb)
{
    const int K = 1024;
    __shared__ ushort_t As[128 * 32];
    __shared__ ushort_t Bs[128 * 32];

    int t = threadIdx.x;
    int m0 = blockIdx.x * 128;
    int y = blockIdx.y;
    int region = y >> 3;
    int n0 = (y & 7) * 128;

    int lane = t & 63, w = t >> 6;
    int lm = lane & 15, quad = lane >> 4;
    int wm = (w >> 1) * 64, wn = (w & 1) * 64;

    f4 acc[4][4] = {};

    const ushort_t* pA = &A[(size_t)(m0 + (t >> 2)) * K + (t & 3) * 8];
    const ushort_t* pB = &Wt3[(size_t)(y * 128 + (t >> 2)) * K + (t & 3) * 8];
    ushort_t* lA = &As[t * 8];
    ushort_t* lB = &Bs[t * 8];
    const size_t rstep = (size_t)64 * K;

    for (int k0 = 0; k0 < K; k0 += 32) {
        gl2lds16(pA, lA);
        gl2lds16(pA + rstep, lA + 2048);
        gl2lds16(pB, lB);
        gl2lds16(pB + rstep, lB + 2048);
        pA += 32; pB += 32;
        __syncthreads();

        bf8 af[4], bfr[4];
        #pragma unroll
        for (int mi = 0; mi < 4; mi++)
            af[mi] = *(bf8*)&As[(wm + mi * 16 + lm) * 32 + quad * 8];
        #pragma unroll
        for (int ni = 0; ni < 4; ni++)
            bfr[ni] = *(bf8*)&Bs[(wn + ni * 16 + lm) * 32 + quad * 8];
        if (region == 2) {
            #pragma unroll
            for (int mi = 0; mi < 4; mi++)
            #pragma unroll
            for (int ni = 0; ni < 4; ni++)
                acc[mi][ni] = __builtin_amdgcn_mfma_f32_16x16x32_bf16(af[mi], bfr[ni], acc[mi][ni], 0, 0, 0);
        } else {
            #pragma unroll
            for (int ni = 0; ni < 4; ni++)
            #pragma unroll
            for (int mi = 0; mi < 4; mi++)
                acc[ni][mi] = __builtin_amdgcn_mfma_f32_16x16x32_bf16(bfr[ni], af[mi], acc[ni][mi], 0, 0, 0);
        }
        __syncthreads();
    }

    if (region == 0) {
        int head = (n0 + wn) >> 6;
        float sp = log1pf(__expf(temp[head]));
        f4 bv4[4], ev4[4];
        #pragma unroll
        for (int ni = 0; ni < 4; ni++) {
            bv4[ni] = *(const f4*)&bq[n0 + wn + ni * 16 + quad * 4];
            ev4[ni] = *(const f4*)&emb[head * 64 + ni * 16 + quad * 4];
        }
        #pragma unroll
        for (int mi = 0; mi < 4; mi++) {
            float v[4][4];
            float ss = 0.f;
            #pragma unroll
            for (int ni = 0; ni < 4; ni++)
            #pragma unroll
            for (int i = 0; i < 4; i++) {
                v[ni][i] = acc[ni][mi][i] + bv4[ni][i];
                ss += v[ni][i] * v[ni][i];
            }
            ss += __shfl_xor(ss, 16, 64);
            ss += __shfl_xor(ss, 32, 64);
            float rs = rsqrtf(ss + 1e-12f);
            int tok = m0 + wm + mi * 16 + lm;
            int b = tok >> 11, s = tok & 2047;
            size_t rowb = (((size_t)(b * 16 + head)) * 2048 + s) * 64;
            #pragma unroll
            for (int ni = 0; ni < 4; ni++) {
                uint2 o;
                o.x = pack2bf((v[ni][0] * rs + ev4[ni][0]) * sp * 0.125f,
                              (v[ni][1] * rs + ev4[ni][1]) * sp * 0.125f);
                o.y = pack2bf((v[ni][2] * rs + ev4[ni][2]) * sp * 0.125f,
                              (v[ni][3] * rs + ev4[ni][3]) * sp * 0.125f);
                *(uint2*)&Qb[rowb + ni * 16 + quad * 4] = o;
            }
        }
    } else if (region == 1) {
        int head = (n0 + wn) >> 6;
        f4 bv4[4];
        #pragma unroll
        for (int ni = 0; ni < 4; ni++)
            bv4[ni] = *(const f4*)&bk[n0 + wn + ni * 16 + quad * 4];
        #pragma unroll
        for (int mi = 0; mi < 4; mi++) {
            int tok = m0 + wm + mi * 16 + lm;
            int b = tok >> 11, s = tok & 2047;
            size_t rowb = (((size_t)(b * 16 + head)) * 2048 + s) * 64;
            #pragma unroll
            for (int ni = 0; ni < 4; ni++) {
                uint2 o;
                o.x = pack2bf(acc[ni][mi][0] + bv4[ni][0], acc[ni][mi][1] + bv4[ni][1]);
                o.y = pack2bf(acc[ni][mi][2] + bv4[ni][2], acc[ni][mi][3] + bv4[ni][3]);
                *(uint2*)&Kw[rowb + ni * 16 + quad * 4] = o;
            }
        }
    } else {
        float bvv[4];
        #pragma unroll
        for (int ni = 0; ni < 4; ni++) bvv[ni] = bv[n0 + wn + ni * 16 + lm];
        #pragma unroll
        for (int mi = 0; mi < 4; mi++) {
            int gr0 = m0 + wm + mi * 16 + quad * 4;
            int b = gr0 >> 11, s0 = gr0 & 2047;
            #pragma unroll
            for (int ni = 0; ni < 4; ni++) {
                int gc = n0 + wn + ni * 16 + lm;
                int h = gc >> 6, d = gc & 63;
                uint2 o;
                o.x = pack2bf(acc[mi][ni][0] + bvv[ni], acc[mi][ni][1] + bvv[ni]);
                o.y = pack2bf(acc[mi][ni][2] + bvv[ni], acc[mi][ni][3] + bvv[ni]);
                *(uint2*)&VTw[(((size_t)(b * 16 + h)) * 64 + d) * 2048 + s0] = o;
            }
        }
    }
}

// ---------------------------------------------------------------------------
// Output projection GEMM, swapped operands, fused per-token gate scale.
// ---------------------------------------------------------------------------
__global__ __launch_bounds__(256)
void gemmP(const ushort_t* __restrict__ A, const ushort_t* __restrict__ Wt,
           const float* __restrict__ bias, const float* __restrict__ G,
           float* __restrict__ out, int M, int N, int K)
{
    __shared__ ushort_t As[128 * 32];
    __shared__ ushort_t Bs[128 * 32];

    int t = threadIdx.x;
    int m0 = blockIdx.x * 128, n0 = blockIdx.y * 128;
    int lane = t & 63, w = t >> 6;
    int lm = lane & 15, quad = lane >> 4;
    int wm = (w >> 1) * 64, wn = (w & 1) * 64;

    f4 acc[4][4] = {};

    const ushort_t* pA = &A[(size_t)(m0 + (t >> 2)) * K + (t & 3) * 8];
    const ushort_t* pB = &Wt[(size_t)(n0 + (t >> 2)) * K + (t & 3) * 8];
    ushort_t* lA = &As[t * 8];
    ushort_t* lB = &Bs[t * 8];
    const size_t rstep = (size_t)64 * K;

    for (int k0 = 0; k0 < K; k0 += 32) {
        gl2lds16(pA, lA);
        gl2lds16(pA + rstep, lA + 2048);
        gl2lds16(pB, lB);
        gl2lds16(pB + rstep, lB + 2048);
        pA += 32; pB += 32;
        __syncthreads();

        bf8 af[4], bfr[4];
        #pragma unroll
        for (int mi = 0; mi < 4; mi++)
            af[mi] = *(bf8*)&As[(wm + mi * 16 + lm) * 32 + quad * 8];
        #pragma unroll
        for (int ni = 0; ni < 4; ni++)
            bfr[ni] = *(bf8*)&Bs[(wn + ni * 16 + lm) * 32 + quad * 8];
        #pragma unroll
        for (int ni = 0; ni < 4; ni++)
        #pragma unroll
        for (int mi = 0; mi < 4; mi++)
            acc[ni][mi] = __builtin_amdgcn_mfma_f32_16x16x32_bf16(bfr[ni], af[mi], acc[ni][mi], 0, 0, 0);
        __syncthreads();
    }

    f4 bv4[4];
    #pragma unroll
    for (int ni = 0; ni < 4; ni++)
        bv4[ni] = *(const f4*)&bias[n0 + wn + ni * 16 + quad * 4];
    #pragma unroll
    for (int mi = 0; mi < 4; mi++) {
        int tok = m0 + wm + mi * 16 + lm;
        float g = G[tok];
        size_t rowb = (size_t)tok * N + n0 + wn;
        #pragma unroll
        for (int ni = 0; ni < 4; ni++) {
            f4 o;
            #pragma unroll
            for (int i = 0; i < 4; i++) o[i] = g * acc[ni][mi][i] + bv4[ni][i];
            *(f4*)&out[rowb + ni * 16 + quad * 4] = o;
        }
    }
}

// ---------------------------------------------------------------------------
// Flash MFMA attention v3: 32x32x16 MFMA + split-K=2.
// Grid 1024 = 32 bh x 16 qt x 2 ks; each block does 1024 keys, writes raw
// partial numerator O (bf16, [ks][B,H,S,64]) and partial l (fp32).
// Fixed-m softmax => combine is linear: O=(P0+P1)/(l0+l1).
// ---------------------------------------------------------------------------
__global__ __launch_bounds__(256)
void attn(const ushort_t* __restrict__ Q, const ushort_t* __restrict__ K,
          const ushort_t* __restrict__ VT, ushort_t* __restrict__ Opart,
          float* __restrict__ Lw)
{
    __shared__ ushort_t Ks[64 * 72];       // [key][dim]
    __shared__ ushort_t Vt[64 * 72];       // [dim][key]
    __shared__ ushort_t Ps[4][32 * 72];    // per-wave P[q][key]

    int t = threadIdx.x, lane = t & 63, w = t >> 6;
    int l31 = lane & 31, hi = lane >> 5;
    int bid = blockIdx.x;
    int bh = bid & 31, qt = (bid >> 5) & 15, ks = bid >> 9;
    size_t base = (size_t)bh * 2048 * 64;

    int tok = qt * 128 + w * 32 + l31;
    const ushort_t* qp = &Q[base + (size_t)tok * 64 + hi * 8];
    bf8 qa[4];
    #pragma unroll
    for (int c = 0; c < 4; c++) qa[c] = *(const bf8*)(qp + c * 16);

    float l_part = 0.f;
    f16v o_acc[2] = {};

    int sr = t >> 3, sc = (t & 7) * 8;
    const ushort_t* kg0 = &K[base + (size_t)sr * 64 + sc];
    const ushort_t* vg0 = &VT[base + (size_t)sr * 2048 + sc];

    int kend = ks * 1024 + 1024;
    for (int kb = ks * 1024; kb < kend; kb += 64) {
        __syncthreads();
        {
            uint4 k0 = *(const uint4*)(kg0 + (size_t)kb * 64);
            uint4 k1 = *(const uint4*)(kg0 + (size_t)(kb + 32) * 64);
            uint4 v0 = *(const uint4*)(vg0 + kb);
            uint4 v1 = *(const uint4*)(vg0 + 32 * 2048 + kb);
            *(uint4*)&Ks[sr * 72 + sc] = k0;
            *(uint4*)&Ks[(sr + 32) * 72 + sc] = k1;
            *(uint4*)&Vt[sr * 72 + sc] = v0;
            *(uint4*)&Vt[(sr + 32) * 72 + sc] = v1;
        }
        __syncthreads();

        ushort_t* pw = &Ps[w][0];
        #pragma unroll
        for (int kt2 = 0; kt2 < 2; kt2++) {
            f16v s = {};
            #pragma unroll
            for (int c = 0; c < 4; c++) {
                bf8 kf = *(bf8*)&Ks[(kt2 * 32 + l31) * 72 + c * 16 + hi * 8];
                s = __builtin_amdgcn_mfma_f32_32x32x16_bf16(kf, qa[c], s, 0, 0, 0);
            }
            #pragma unroll
            for (int g = 0; g < 4; g++) {
                float p0 = __expf(s[g * 4 + 0]);
                float p1 = __expf(s[g * 4 + 1]);
                float p2 = __expf(s[g * 4 + 2]);
                float p3 = __expf(s[g * 4 + 3]);
                l_part += (p0 + p1) + (p2 + p3);
                int k0i = kt2 * 32 + g * 8 + hi * 4;
                *(uint_t*)&pw[l31 * 72 + k0i]     = pack2bf_fast(p0, p1);
                *(uint_t*)&pw[l31 * 72 + k0i + 2] = pack2bf_fast(p2, p3);
            }
        }

        #pragma unroll
        for (int c = 0; c < 4; c++) {
            bf8 pf = *(bf8*)&pw[l31 * 72 + c * 16 + hi * 8];
            #pragma unroll
            for (int dt = 0; dt < 2; dt++) {
                bf8 vf = *(bf8*)&Vt[(dt * 32 + l31) * 72 + c * 16 + hi * 8];
                o_acc[dt] = __builtin_amdgcn_mfma_f32_32x32x16_bf16(vf, pf, o_acc[dt], 0, 0, 0);
            }
        }
    }

    l_part += __shfl_xor(l_part, 32, 64);
    if (hi == 0) Lw[((size_t)ks * 32 + bh) * 2048 + tok] = l_part;

    size_t pbase = (((size_t)(ks * 32 + bh)) * 2048 + tok) * 64;
    #pragma unroll
    for (int dt = 0; dt < 2; dt++)
    #pragma unroll
    for (int g = 0; g < 4; g++) {
        int d0 = dt * 32 + g * 8 + hi * 4;
        uint2 o;
        o.x = pack2bf_fast(o_acc[dt][g * 4 + 0], o_acc[dt][g * 4 + 1]);
        o.y = pack2bf_fast(o_acc[dt][g * 4 + 2], o_acc[dt][g * 4 + 3]);
        *(uint2*)&Opart[pbase + d0] = o;
    }
}

// ---------------------------------------------------------------------------
// Combine split-K partials: Ob[b,s,h*64+d] = (P0+P1)/(l0+l1), bf16 out.
// ---------------------------------------------------------------------------
__global__ __launch_bounds__(256)
void combine(const ushort_t* __restrict__ Opart, const float* __restrict__ Lw,
             ushort_t* __restrict__ Ob)
{
    int i = blockIdx.x * 256 + threadIdx.x;   // 4 elems/thread
    int flat = i * 4;
    int row = flat >> 6;                      // bh*2048 + tok
    int d = flat & 63;
    int bh = row >> 11, tok = row & 2047;
    int b = bh >> 4, h = bh & 15;
    float rl = 1.f / (Lw[row] + Lw[65536 + row]);
    uint2 p0 = *(const uint2*)&Opart[flat];
    uint2 p1 = *(const uint2*)&Opart[4194304 + flat];
    float v0 = (bf2f(p0.x & 0xffff) + bf2f(p1.x & 0xffff)) * rl;
    float v1 = (bf2f(p0.x >> 16)   + bf2f(p1.x >> 16))   * rl;
    float v2 = (bf2f(p0.y & 0xffff) + bf2f(p1.y & 0xffff)) * rl;
    float v3 = (bf2f(p0.y >> 16)   + bf2f(p1.y >> 16))   * rl;
    uint2 o;
    o.x = pack2bf(v0, v1);
    o.y = pack2bf(v2, v3);
    *(uint2*)&Ob[((size_t)(b * 2048 + tok)) * 1024 + h * 64 + d] = o;
}

// ---------------------------------------------------------------------------
// MFMA router: logits[64 tok][17] = Ob @ Wg^T -> per-token gate scalar.
// ---------------------------------------------------------------------------
__global__ __launch_bounds__(256)
void router(const ushort_t* __restrict__ O, const ushort_t* __restrict__ Wg,
            const float* __restrict__ br, const float* __restrict__ bs,
            float* __restrict__ G)
{
    __shared__ float Ls[64][21];
    int t = threadIdx.x, lane = t & 63, w = t >> 6;
    int lm = lane & 15, quad = lane >> 4;
    int tok0 = blockIdx.x * 64;

    const ushort_t* ap = &O[(size_t)(tok0 + w * 16 + lm) * 1024 + quad * 8];
    const ushort_t* b0p = &Wg[(size_t)lm * 1024 + quad * 8];
    const ushort_t* b1p = &Wg[(size_t)(16 + lm) * 1024 + quad * 8];

    f4 acc0 = {}, acc1 = {};
    for (int k0 = 0; k0 < 1024; k0 += 32) {
        bf8 a = *(const bf8*)(ap + k0);
        bf8 b0 = *(const bf8*)(b0p + k0);
        bf8 b1 = *(const bf8*)(b1p + k0);
        acc0 = __builtin_amdgcn_mfma_f32_16x16x32_bf16(a, b0, acc0, 0, 0, 0);
        acc1 = __builtin_amdgcn_mfma_f32_16x16x32_bf16(a, b1, acc1, 0, 0, 0);
    }
    #pragma unroll
    for (int i = 0; i < 4; i++) {
        int tl = w * 16 + quad * 4 + i;
        Ls[tl][lm] = acc0[i];
        if (lm == 0) Ls[tl][16] = acc1[i];
    }
    __syncthreads();
    if (t < 64) {
        float v[15];
        float mx = -1e30f;
        #pragma unroll
        for (int c = 0; c < 15; c++) { v[c] = Ls[t][c] + br[c]; mx = fmaxf(mx, v[c]); }
        float sum = 0.f;
        #pragma unroll
        for (int c = 0; c < 15; c++) { v[c] = __expf(v[c] - mx); sum += v[c]; }
        float inv = 1.f / sum;
        float t3 = 0.f;
        for (int r = 0; r < 3; r++) {
            int bi = 0; float bv = -1e30f;
            #pragma unroll
            for (int c = 0; c < 15; c++) if (v[c] > bv) { bv = v[c]; bi = c; }
            t3 += bv; v[bi] = -1e30f;
        }
        t3 *= inv;
        float a0 = Ls[t][15] + bs[0], a1 = Ls[t][16] + bs[1];
        float m2 = fmaxf(a0, a1);
        float e0 = __expf(a0 - m2), e1 = __expf(a1 - m2);
        G[tok0 + t] = (2.f * e0 + 6.f * e1 * t3) / (e0 + e1);
    }
}

// ---------------------------------------------------------------------------
extern "C" void kernel_launch(void* const* d_in, const int* in_sizes, int n_in,
                              void* d_out, int out_size, void* d_ws, size_t ws_size,
                              hipStream_t stream)
{
    const float* x     = (const float*)d_in[0];
    const float* Wq    = (const float*)d_in[1];
    const float* bq    = (const float*)d_in[2];
    const float* Wk    = (const float*)d_in[3];
    const float* bk    = (const float*)d_in[4];
    const float* Wv    = (const float*)d_in[5];
    const float* bv    = (const float*)d_in[6];
    const float* Wproj = (const float*)d_in[7];
    const float* bproj = (const float*)d_in[8];
    const float* Wr    = (const float*)d_in[9];
    const float* br    = (const float*)d_in[10];
    const float* Ws    = (const float*)d_in[11];
    const float* bs    = (const float*)d_in[12];
    const float* temp  = (const float*)d_in[13];
    const float* emb   = (const float*)d_in[14];

    const int M = 4096, N = 1024, Kd = 1024;

    char* ws = (char*)d_ws;
    ushort_t* Kw    = (ushort_t*)ws;                    //  8 MB [B,H,S,64]
    ushort_t* VTw   = (ushort_t*)(ws + 8388608);        //  8 MB [B,H,64,S]
    ushort_t* Qb    = (ushort_t*)(ws + 16777216);       //  8 MB Q; Ob after attn
    ushort_t* Wtp   = (ushort_t*)(ws + 25165824);       //  2 MB Wproj^T
    float*    Gw    = (float*)(ws + 27262976);          // 16 KB
    ushort_t* Wg    = (ushort_t*)(ws + 27279360);       // 64 KB
    float*    Lw    = (float*)(ws + 27344896);          // 512 KB [2][32][2048]
    ushort_t* Wt3   = (ushort_t*)(ws + 27869184);       //  6 MB (dead after QKV)
    ushort_t* xb    = (ushort_t*)(ws + 34160640);       //  8 MB (dead after QKV)
    ushort_t* Opart = (ushort_t*)(ws + 27869184);       // 16 MB, overlays Wt3+xb
    ushort_t* Ob    = Qb;                               // combine writes over Q

    prep<<<8320, 256, 0, stream>>>(x, xb, Wr, Ws, Wg, Wq, Wk, Wv, Wproj,
        Wt3, Wt3 + 1048576, Wt3 + 2097152, Wtp);

    gemmQKV<<<dim3(32, 24), 256, 0, stream>>>(xb, Wt3, bq, bk, bv,
        Qb, Kw, VTw, temp, emb);

    attn<<<1024, 256, 0, stream>>>(Qb, Kw, VTw, Opart, Lw);

    combine<<<4096, 256, 0, stream>>>(Opart, Lw, Ob);

    router<<<64, 256, 0, stream>>>(Ob, Wg, br, bs, Gw);

    gemmP<<<dim3(32, 8), 256, 0, stream>>>(Ob, Wtp, bproj, Gw, (float*)d_out, M, N, Kd);
}

// Round 12
// 262.514 us; speedup vs baseline: 1.0103x; 1.0103x over previous
//
#include <hip/hip_runtime.h>
#include <hip/hip_bf16.h>

typedef unsigned short ushort_t;
typedef unsigned int uint_t;

typedef __attribute__((ext_vector_type(8))) short bf8;
typedef __attribute__((ext_vector_type(4))) float f4;
typedef __attribute__((ext_vector_type(16))) float f16v;

__device__ __forceinline__ float bf2f(ushort_t u) {
    unsigned int x = ((unsigned int)u) << 16;
    return __uint_as_float(x);
}
__device__ __forceinline__ ushort_t f2bf(float f) {
    unsigned int x = __float_as_uint(f);
    unsigned int r = x + 0x7fffu + ((x >> 16) & 1u);
    return (ushort_t)(r >> 16);
}
__device__ __forceinline__ uint_t pack2bf(float a, float b) {
    return (uint_t)f2bf(a) | ((uint_t)f2bf(b) << 16);
}
// fast pack: round-half-up + v_perm_b32 byte gather (3 VALU vs ~9)
__device__ __forceinline__ uint_t pack2bf_fast(float a, float b) {
    uint_t au = __float_as_uint(a) + 0x8000u;
    uint_t bu = __float_as_uint(b) + 0x8000u;
    return __builtin_amdgcn_perm(bu, au, 0x07060302);  // lo16=a_hi, hi16=b_hi
}

__device__ __forceinline__ void gl2lds16(const ushort_t* g, ushort_t* l) {
    __builtin_amdgcn_global_load_lds(
        (const __attribute__((address_space(1))) void*)g,
        (__attribute__((address_space(3))) void*)l, 16, 0, 0);
}

// ---------------------------------------------------------------------------
// prep (merged): [0,4096) x fp32->bf16; [4096,4224) Wg pack; [4224,8320)
// weight transpose-convert (4 matrices, 32x32 tiles)
// ---------------------------------------------------------------------------
__global__ __launch_bounds__(256)
void prep(const float* __restrict__ x, ushort_t* __restrict__ xb,
          const float* __restrict__ Wr, const float* __restrict__ Ws,
          ushort_t* __restrict__ Wg,
          const float* __restrict__ W0, const float* __restrict__ W1,
          const float* __restrict__ W2, const float* __restrict__ W3,
          ushort_t* __restrict__ T0, ushort_t* __restrict__ T1,
          ushort_t* __restrict__ T2, ushort_t* __restrict__ T3)
{
    __shared__ float tile[32][33];
    int bid = blockIdx.x;
    int t = threadIdx.x;
    if (bid < 4096) {
        int i = bid * 256 + t;
        float4 v = ((const float4*)x)[i];
        uint2 o;
        o.x = pack2bf(v.x, v.y);
        o.y = pack2bf(v.z, v.w);
        ((uint2*)xb)[i] = o;
    } else if (bid < 4224) {
        int idx = (bid - 4096) * 256 + t;   // 32 x 1024
        int c = idx >> 10, d = idx & 1023;
        float v = 0.f;
        if (c < 15) v = Wr[(size_t)d * 15 + c];
        else if (c < 17) v = Ws[(size_t)d * 2 + (c - 15)];
        Wg[idx] = f2bf(v);
    } else {
        int idx = bid - 4224;               // 4 x 32 x 32 tiles
        int z = idx >> 10, r10 = idx & 1023;
        int k0 = (r10 & 31) * 32, n0 = (r10 >> 5) * 32;
        const float* W; ushort_t* T;
        switch (z) {
            case 0: W = W0; T = T0; break;
            case 1: W = W1; T = T1; break;
            case 2: W = W2; T = T2; break;
            default: W = W3; T = T3; break;
        }
        int r = t >> 3, c4 = (t & 7) * 4;
        float4 v = *(const float4*)&W[(size_t)(k0 + r) * 1024 + n0 + c4];
        tile[r][c4 + 0] = v.x; tile[r][c4 + 1] = v.y;
        tile[r][c4 + 2] = v.z; tile[r][c4 + 3] = v.w;
        __syncthreads();
        int n = t >> 3, kk = (t & 7) * 4;
        uint2 o;
        o.x = pack2bf(tile[kk][n], tile[kk + 1][n]);
        o.y = pack2bf(tile[kk + 2][n], tile[kk + 3][n]);
        *(uint2*)&T[(size_t)(n0 + n) * 1024 + k0 + kk] = o;
    }
}

// ---------------------------------------------------------------------------
// Fused QKV GEMM: [4096x1024] @ Wt3[3072,1024]^T. Grid (32, 24).
// region = y>>3: 0=Q, 1=K, 2=V. (unchanged)
// ---------------------------------------------------------------------------
__global__ __launch_bounds__(256)
void gemmQKV(const ushort_t* __restrict__ A, const ushort_t* __restrict__ Wt3,
             const float* __restrict__ bq, const float* __restrict__ bk,
             const float* __restrict__ bv,
             ushort_t* __restrict__ Qb, ushort_t* __restrict__ Kw,
             ushort_t* __restrict__ VTw,
             const float* __restrict__ temp, const float* __restrict__ emb)
{
    const int K = 1024;
    __shared__ ushort_t As[128 * 32];
    __shared__ ushort_t Bs[128 * 32];

    int t = threadIdx.x;
    int m0 = blockIdx.x * 128;
    int y = blockIdx.y;
    int region = y >> 3;
    int n0 = (y & 7) * 128;

    int lane = t & 63, w = t >> 6;
    int lm = lane & 15, quad = lane >> 4;
    int wm = (w >> 1) * 64, wn = (w & 1) * 64;

    f4 acc[4][4] = {};

    const ushort_t* pA = &A[(size_t)(m0 + (t >> 2)) * K + (t & 3) * 8];
    const ushort_t* pB = &Wt3[(size_t)(y * 128 + (t >> 2)) * K + (t & 3) * 8];
    ushort_t* lA = &As[t * 8];
    ushort_t* lB = &Bs[t * 8];
    const size_t rstep = (size_t)64 * K;

    for (int k0 = 0; k0 < K; k0 += 32) {
        gl2lds16(pA, lA);
        gl2lds16(pA + rstep, lA + 2048);
        gl2lds16(pB, lB);
        gl2lds16(pB + rstep, lB + 2048);
        pA += 32; pB += 32;
        __syncthreads();

        bf8 af[4], bfr[4];
        #pragma unroll
        for (int mi = 0; mi < 4; mi++)
            af[mi] = *(bf8*)&As[(wm + mi * 16 + lm) * 32 + quad * 8];
        #pragma unroll
        for (int ni = 0; ni < 4; ni++)
            bfr[ni] = *(bf8*)&Bs[(wn + ni * 16 + lm) * 32 + quad * 8];
        if (region == 2) {
            #pragma unroll
            for (int mi = 0; mi < 4; mi++)
            #pragma unroll
            for (int ni = 0; ni < 4; ni++)
                acc[mi][ni] = __builtin_amdgcn_mfma_f32_16x16x32_bf16(af[mi], bfr[ni], acc[mi][ni], 0, 0, 0);
        } else {
            #pragma unroll
            for (int ni = 0; ni < 4; ni++)
            #pragma unroll
            for (int mi = 0; mi < 4; mi++)
                acc[ni][mi] = __builtin_amdgcn_mfma_f32_16x16x32_bf16(bfr[ni], af[mi], acc[ni][mi], 0, 0, 0);
        }
        __syncthreads();
    }

    if (region == 0) {
        int head = (n0 + wn) >> 6;
        float sp = log1pf(__expf(temp[head]));
        f4 bv4[4], ev4[4];
        #pragma unroll
        for (int ni = 0; ni < 4; ni++) {
            bv4[ni] = *(const f4*)&bq[n0 + wn + ni * 16 + quad * 4];
            ev4[ni] = *(const f4*)&emb[head * 64 + ni * 16 + quad * 4];
        }
        #pragma unroll
        for (int mi = 0; mi < 4; mi++) {
            float v[4][4];
            float ss = 0.f;
            #pragma unroll
            for (int ni = 0; ni < 4; ni++)
            #pragma unroll
            for (int i = 0; i < 4; i++) {
                v[ni][i] = acc[ni][mi][i] + bv4[ni][i];
                ss += v[ni][i] * v[ni][i];
            }
            ss += __shfl_xor(ss, 16, 64);
            ss += __shfl_xor(ss, 32, 64);
            float rs = rsqrtf(ss + 1e-12f);
            int tok = m0 + wm + mi * 16 + lm;
            int b = tok >> 11, s = tok & 2047;
            size_t rowb = (((size_t)(b * 16 + head)) * 2048 + s) * 64;
            #pragma unroll
            for (int ni = 0; ni < 4; ni++) {
                uint2 o;
                o.x = pack2bf((v[ni][0] * rs + ev4[ni][0]) * sp * 0.125f,
                              (v[ni][1] * rs + ev4[ni][1]) * sp * 0.125f);
                o.y = pack2bf((v[ni][2] * rs + ev4[ni][2]) * sp * 0.125f,
                              (v[ni][3] * rs + ev4[ni][3]) * sp * 0.125f);
                *(uint2*)&Qb[rowb + ni * 16 + quad * 4] = o;
            }
        }
    } else if (region == 1) {
        int head = (n0 + wn) >> 6;
        f4 bv4[4];
        #pragma unroll
        for (int ni = 0; ni < 4; ni++)
            bv4[ni] = *(const f4*)&bk[n0 + wn + ni * 16 + quad * 4];
        #pragma unroll
        for (int mi = 0; mi < 4; mi++) {
            int tok = m0 + wm + mi * 16 + lm;
            int b = tok >> 11, s = tok & 2047;
            size_t rowb = (((size_t)(b * 16 + head)) * 2048 + s) * 64;
            #pragma unroll
            for (int ni = 0; ni < 4; ni++) {
                uint2 o;
                o.x = pack2bf(acc[ni][mi][0] + bv4[ni][0], acc[ni][mi][1] + bv4[ni][1]);
                o.y = pack2bf(acc[ni][mi][2] + bv4[ni][2], acc[ni][mi][3] + bv4[ni][3]);
                *(uint2*)&Kw[rowb + ni * 16 + quad * 4] = o;
            }
        }
    } else {
        float bvv[4];
        #pragma unroll
        for (int ni = 0; ni < 4; ni++) bvv[ni] = bv[n0 + wn + ni * 16 + lm];
        #pragma unroll
        for (int mi = 0; mi < 4; mi++) {
            int gr0 = m0 + wm + mi * 16 + quad * 4;
            int b = gr0 >> 11, s0 = gr0 & 2047;
            #pragma unroll
            for (int ni = 0; ni < 4; ni++) {
                int gc = n0 + wn + ni * 16 + lm;
                int h = gc >> 6, d = gc & 63;
                uint2 o;
                o.x = pack2bf(acc[mi][ni][0] + bvv[ni], acc[mi][ni][1] + bvv[ni]);
                o.y = pack2bf(acc[mi][ni][2] + bvv[ni], acc[mi][ni][3] + bvv[ni]);
                *(uint2*)&VTw[(((size_t)(b * 16 + h)) * 64 + d) * 2048 + s0] = o;
            }
        }
    }
}

// ---------------------------------------------------------------------------
// Output projection GEMM, swapped operands, fused per-token gate scale.
// ---------------------------------------------------------------------------
__global__ __launch_bounds__(256)
void gemmP(const ushort_t* __restrict__ A, const ushort_t* __restrict__ Wt,
           const float* __restrict__ bias, const float* __restrict__ G,
           float* __restrict__ out, int M, int N, int K)
{
    __shared__ ushort_t As[128 * 32];
    __shared__ ushort_t Bs[128 * 32];

    int t = threadIdx.x;
    int m0 = blockIdx.x * 128, n0 = blockIdx.y * 128;
    int lane = t & 63, w = t >> 6;
    int lm = lane & 15, quad = lane >> 4;
    int wm = (w >> 1) * 64, wn = (w & 1) * 64;

    f4 acc[4][4] = {};

    const ushort_t* pA = &A[(size_t)(m0 + (t >> 2)) * K + (t & 3) * 8];
    const ushort_t* pB = &Wt[(size_t)(n0 + (t >> 2)) * K + (t & 3) * 8];
    ushort_t* lA = &As[t * 8];
    ushort_t* lB = &Bs[t * 8];
    const size_t rstep = (size_t)64 * K;

    for (int k0 = 0; k0 < K; k0 += 32) {
        gl2lds16(pA, lA);
        gl2lds16(pA + rstep, lA + 2048);
        gl2lds16(pB, lB);
        gl2lds16(pB + rstep, lB + 2048);
        pA += 32; pB += 32;
        __syncthreads();

        bf8 af[4], bfr[4];
        #pragma unroll
        for (int mi = 0; mi < 4; mi++)
            af[mi] = *(bf8*)&As[(wm + mi * 16 + lm) * 32 + quad * 8];
        #pragma unroll
        for (int ni = 0; ni < 4; ni++)
            bfr[ni] = *(bf8*)&Bs[(wn + ni * 16 + lm) * 32 + quad * 8];
        #pragma unroll
        for (int ni = 0; ni < 4; ni++)
        #pragma unroll
        for (int mi = 0; mi < 4; mi++)
            acc[ni][mi] = __builtin_amdgcn_mfma_f32_16x16x32_bf16(bfr[ni], af[mi], acc[ni][mi], 0, 0, 0);
        __syncthreads();
    }

    f4 bv4[4];
    #pragma unroll
    for (int ni = 0; ni < 4; ni++)
        bv4[ni] = *(const f4*)&bias[n0 + wn + ni * 16 + quad * 4];
    #pragma unroll
    for (int mi = 0; mi < 4; mi++) {
        int tok = m0 + wm + mi * 16 + lm;
        float g = G[tok];
        size_t rowb = (size_t)tok * N + n0 + wn;
        #pragma unroll
        for (int ni = 0; ni < 4; ni++) {
            f4 o;
            #pragma unroll
            for (int i = 0; i < 4; i++) o[i] = g * acc[ni][mi][i] + bv4[ni][i];
            *(f4*)&out[rowb + ni * 16 + quad * 4] = o;
        }
    }
}

// ---------------------------------------------------------------------------
// Flash MFMA attention v4: 32x32x16 MFMA + split-K=2 + register-only P
// transform. The C-layout -> B-frag exchange is 2 shfl_xor(32) + cndmask per
// 16-key chunk (derived lane map: C key rows g*8+hi*4+i vs frag keys
// c*16+hi*8+j -> each lane keeps 4, takes 4 from xor-32 partner).
// No Ps LDS: 18.4 KB total -> occupancy up; zero P bank conflicts.
// ---------------------------------------------------------------------------
__global__ __launch_bounds__(256)
void attn(const ushort_t* __restrict__ Q, const ushort_t* __restrict__ K,
          const ushort_t* __restrict__ VT, ushort_t* __restrict__ Opart,
          float* __restrict__ Lw)
{
    __shared__ ushort_t Ks[64 * 72];       // [key][dim]
    __shared__ ushort_t Vt[64 * 72];       // [dim][key]

    int t = threadIdx.x, lane = t & 63, w = t >> 6;
    int l31 = lane & 31;
    uint_t hi = lane >> 5;
    int bid = blockIdx.x;
    int bh = bid & 31, qt = (bid >> 5) & 15, ks = bid >> 9;
    size_t base = (size_t)bh * 2048 * 64;

    int tok = qt * 128 + w * 32 + l31;
    const ushort_t* qp = &Q[base + (size_t)tok * 64 + hi * 8];
    bf8 qa[4];
    #pragma unroll
    for (int c = 0; c < 4; c++) qa[c] = *(const bf8*)(qp + c * 16);

    float l_part = 0.f;
    f16v o_acc[2] = {};

    int sr = t >> 3, sc = (t & 7) * 8;
    const ushort_t* kg0 = &K[base + (size_t)sr * 64 + sc];
    const ushort_t* vg0 = &VT[base + (size_t)sr * 2048 + sc];

    int kend = ks * 1024 + 1024;
    for (int kb = ks * 1024; kb < kend; kb += 64) {
        __syncthreads();
        {
            uint4 k0 = *(const uint4*)(kg0 + (size_t)kb * 64);
            uint4 k1 = *(const uint4*)(kg0 + (size_t)(kb + 32) * 64);
            uint4 v0 = *(const uint4*)(vg0 + kb);
            uint4 v1 = *(const uint4*)(vg0 + 32 * 2048 + kb);
            *(uint4*)&Ks[sr * 72 + sc] = k0;
            *(uint4*)&Ks[(sr + 32) * 72 + sc] = k1;
            *(uint4*)&Vt[sr * 72 + sc] = v0;
            *(uint4*)&Vt[(sr + 32) * 72 + sc] = v1;
        }
        __syncthreads();

        bf8 pf[4];
        #pragma unroll
        for (int kt2 = 0; kt2 < 2; kt2++) {
            f16v s = {};
            #pragma unroll
            for (int c = 0; c < 4; c++) {
                bf8 kf = *(bf8*)&Ks[(kt2 * 32 + l31) * 72 + c * 16 + hi * 8];
                s = __builtin_amdgcn_mfma_f32_32x32x16_bf16(kf, qa[c], s, 0, 0, 0);
            }
            uint2 pk[4];
            #pragma unroll
            for (int g = 0; g < 4; g++) {
                float p0 = __expf(s[g * 4 + 0]);
                float p1 = __expf(s[g * 4 + 1]);
                float p2 = __expf(s[g * 4 + 2]);
                float p3 = __expf(s[g * 4 + 3]);
                l_part += (p0 + p1) + (p2 + p3);
                pk[g].x = pack2bf_fast(p0, p1);
                pk[g].y = pack2bf_fast(p2, p3);
            }
            #pragma unroll
            for (int cc = 0; cc < 2; cc++) {
                // send own group the partner needs; recv = partner's send
                uint_t sx = hi ? pk[2 * cc].x : pk[2 * cc + 1].x;
                uint_t sy = hi ? pk[2 * cc].y : pk[2 * cc + 1].y;
                uint_t rx = (uint_t)__shfl_xor((int)sx, 32, 64);
                uint_t ry = (uint_t)__shfl_xor((int)sy, 32, 64);
                uint4 u;
                u.x = hi ? rx : pk[2 * cc].x;        // keys j0..3
                u.y = hi ? ry : pk[2 * cc].y;
                u.z = hi ? pk[2 * cc + 1].x : rx;    // keys j4..7
                u.w = hi ? pk[2 * cc + 1].y : ry;
                pf[kt2 * 2 + cc] = *(bf8*)&u;
            }
        }

        #pragma unroll
        for (int c = 0; c < 4; c++) {
            #pragma unroll
            for (int dt = 0; dt < 2; dt++) {
                bf8 vf = *(bf8*)&Vt[(dt * 32 + l31) * 72 + c * 16 + hi * 8];
                o_acc[dt] = __builtin_amdgcn_mfma_f32_32x32x16_bf16(vf, pf[c], o_acc[dt], 0, 0, 0);
            }
        }
    }

    l_part += __shfl_xor(l_part, 32, 64);
    if (hi == 0) Lw[((size_t)ks * 32 + bh) * 2048 + tok] = l_part;

    size_t pbase = (((size_t)(ks * 32 + bh)) * 2048 + tok) * 64;
    #pragma unroll
    for (int dt = 0; dt < 2; dt++)
    #pragma unroll
    for (int g = 0; g < 4; g++) {
        int d0 = dt * 32 + g * 8 + hi * 4;
        uint2 o;
        o.x = pack2bf_fast(o_acc[dt][g * 4 + 0], o_acc[dt][g * 4 + 1]);
        o.y = pack2bf_fast(o_acc[dt][g * 4 + 2], o_acc[dt][g * 4 + 3]);
        *(uint2*)&Opart[pbase + d0] = o;
    }
}

// ---------------------------------------------------------------------------
// Combine split-K partials: Ob[b,s,h*64+d] = (P0+P1)/(l0+l1), bf16 out.
// ---------------------------------------------------------------------------
__global__ __launch_bounds__(256)
void combine(const ushort_t* __restrict__ Opart, const float* __restrict__ Lw,
             ushort_t* __restrict__ Ob)
{
    int i = blockIdx.x * 256 + threadIdx.x;   // 4 elems/thread
    int flat = i * 4;
    int row = flat >> 6;                      // bh*2048 + tok
    int d = flat & 63;
    int bh = row >> 11, tok = row & 2047;
    int b = bh >> 4, h = bh & 15;
    float rl = 1.f / (Lw[row] + Lw[65536 + row]);
    uint2 p0 = *(const uint2*)&Opart[flat];
    uint2 p1 = *(const uint2*)&Opart[4194304 + flat];
    float v0 = (bf2f(p0.x & 0xffff) + bf2f(p1.x & 0xffff)) * rl;
    float v1 = (bf2f(p0.x >> 16)   + bf2f(p1.x >> 16))   * rl;
    float v2 = (bf2f(p0.y & 0xffff) + bf2f(p1.y & 0xffff)) * rl;
    float v3 = (bf2f(p0.y >> 16)   + bf2f(p1.y >> 16))   * rl;
    uint2 o;
    o.x = pack2bf(v0, v1);
    o.y = pack2bf(v2, v3);
    *(uint2*)&Ob[((size_t)(b * 2048 + tok)) * 1024 + h * 64 + d] = o;
}

// ---------------------------------------------------------------------------
// MFMA router: logits[64 tok][17] = Ob @ Wg^T -> per-token gate scalar.
// ---------------------------------------------------------------------------
__global__ __launch_bounds__(256)
void router(const ushort_t* __restrict__ O, const ushort_t* __restrict__ Wg,
            const float* __restrict__ br, const float* __restrict__ bs,
            float* __restrict__ G)
{
    __shared__ float Ls[64][21];
    int t = threadIdx.x, lane = t & 63, w = t >> 6;
    int lm = lane & 15, quad = lane >> 4;
    int tok0 = blockIdx.x * 64;

    const ushort_t* ap = &O[(size_t)(tok0 + w * 16 + lm) * 1024 + quad * 8];
    const ushort_t* b0p = &Wg[(size_t)lm * 1024 + quad * 8];
    const ushort_t* b1p = &Wg[(size_t)(16 + lm) * 1024 + quad * 8];

    f4 acc0 = {}, acc1 = {};
    for (int k0 = 0; k0 < 1024; k0 += 32) {
        bf8 a = *(const bf8*)(ap + k0);
        bf8 b0 = *(const bf8*)(b0p + k0);
        bf8 b1 = *(const bf8*)(b1p + k0);
        acc0 = __builtin_amdgcn_mfma_f32_16x16x32_bf16(a, b0, acc0, 0, 0, 0);
        acc1 = __builtin_amdgcn_mfma_f32_16x16x32_bf16(a, b1, acc1, 0, 0, 0);
    }
    #pragma unroll
    for (int i = 0; i < 4; i++) {
        int tl = w * 16 + quad * 4 + i;
        Ls[tl][lm] = acc0[i];
        if (lm == 0) Ls[tl][16] = acc1[i];
    }
    __syncthreads();
    if (t < 64) {
        float v[15];
        float mx = -1e30f;
        #pragma unroll
        for (int c = 0; c < 15; c++) { v[c] = Ls[t][c] + br[c]; mx = fmaxf(mx, v[c]); }
        float sum = 0.f;
        #pragma unroll
        for (int c = 0; c < 15; c++) { v[c] = __expf(v[c] - mx); sum += v[c]; }
        float inv = 1.f / sum;
        float t3 = 0.f;
        for (int r = 0; r < 3; r++) {
            int bi = 0; float bv = -1e30f;
            #pragma unroll
            for (int c = 0; c < 15; c++) if (v[c] > bv) { bv = v[c]; bi = c; }
            t3 += bv; v[bi] = -1e30f;
        }
        t3 *= inv;
        float a0 = Ls[t][15] + bs[0], a1 = Ls[t][16] + bs[1];
        float m2 = fmaxf(a0, a1);
        float e0 = __expf(a0 - m2), e1 = __expf(a1 - m2);
        G[tok0 + t] = (2.f * e0 + 6.f * e1 * t3) / (e0 + e1);
    }
}

// ---------------------------------------------------------------------------
extern "C" void kernel_launch(void* const* d_in, const int* in_sizes, int n_in,
                              void* d_out, int out_size, void* d_ws, size_t ws_size,
                              hipStream_t stream)
{
    const float* x     = (const float*)d_in[0];
    const float* Wq    = (const float*)d_in[1];
    const float* bq    = (const float*)d_in[2];
    const float* Wk    = (const float*)d_in[3];
    const float* bk    = (const float*)d_in[4];
    const float* Wv    = (const float*)d_in[5];
    const float* bv    = (const float*)d_in[6];
    const float* Wproj = (const float*)d_in[7];
    const float* bproj = (const float*)d_in[8];
    const float* Wr    = (const float*)d_in[9];
    const float* br    = (const float*)d_in[10];
    const float* Ws    = (const float*)d_in[11];
    const float* bs    = (const float*)d_in[12];
    const float* temp  = (const float*)d_in[13];
    const float* emb   = (const float*)d_in[14];

    const int M = 4096, N = 1024, Kd = 1024;

    char* ws = (char*)d_ws;
    ushort_t* Kw    = (ushort_t*)ws;                    //  8 MB [B,H,S,64]
    ushort_t* VTw   = (ushort_t*)(ws + 8388608);        //  8 MB [B,H,64,S]
    ushort_t* Qb    = (ushort_t*)(ws + 16777216);       //  8 MB Q; Ob after attn
    ushort_t* Wtp   = (ushort_t*)(ws + 25165824);       //  2 MB Wproj^T
    float*    Gw    = (float*)(ws + 27262976);          // 16 KB
    ushort_t* Wg    = (ushort_t*)(ws + 27279360);       // 64 KB
    float*    Lw    = (float*)(ws + 27344896);          // 512 KB [2][32][2048]
    ushort_t* Wt3   = (ushort_t*)(ws + 27869184);       //  6 MB (dead after QKV)
    ushort_t* xb    = (ushort_t*)(ws + 34160640);       //  8 MB (dead after QKV)
    ushort_t* Opart = (ushort_t*)(ws + 27869184);       // 16 MB, overlays Wt3+xb
    ushort_t* Ob    = Qb;                               // combine writes over Q

    prep<<<8320, 256, 0, stream>>>(x, xb, Wr, Ws, Wg, Wq, Wk, Wv, Wproj,
        Wt3, Wt3 + 1048576, Wt3 + 2097152, Wtp);

    gemmQKV<<<dim3(32, 24), 256, 0, stream>>>(xb, Wt3, bq, bk, bv,
        Qb, Kw, VTw, temp, emb);

    attn<<<1024, 256, 0, stream>>>(Qb, Kw, VTw, Opart, Lw);

    combine<<<4096, 256, 0, stream>>>(Opart, Lw, Ob);

    router<<<64, 256, 0, stream>>>(Ob, Wg, br, bs, Gw);

    gemmP<<<dim3(32, 8), 256, 0, stream>>>(Ob, Wtp, bproj, Gw, (float*)d_out, M, N, Kd);
}